// Round 7
// baseline (43.592 us; speedup 1.0000x reference)
//
#include <hip/hip_runtime.h>

#define N 8192
#define BLOCK 128
#define ITILE 128                  // 128-wide i-tile, 1 i-point per thread
#define NB (N / ITILE)             // 64
#define NTRI (NB * (NB + 1) / 2)   // 2080 triangular tiles
#define JSPLIT 2
#define JSUB (ITILE / JSPLIT)      // 64 j-points per block
#define NPART (NTRI * JSPLIT)      // 4160 partials

#define RSQ __builtin_amdgcn_rsqf

typedef float f32x2 __attribute__((ext_vector_type(2)));

// 9-image Coulomb sum for a packed j-pair; all full-rate math is element-wise in
// the (jA, jB) packing -> v_pk_{add,mul,fma}_f32. (dx±10)^2 = fma(±20,dx,dx^2+100).
__device__ __forceinline__ f32x2 pair9v(f32x2 dx, f32x2 dy) {
    f32x2 x0 = dx * dx, y0 = dy * dy;
    f32x2 tx = x0 + 100.0f, ty = y0 + 100.0f;
    f32x2 xm = __builtin_elementwise_fma((f32x2)(20.0f), dx, tx);
    f32x2 xp = __builtin_elementwise_fma((f32x2)(-20.0f), dx, tx);
    f32x2 ym = __builtin_elementwise_fma((f32x2)(20.0f), dy, ty);
    f32x2 yp = __builtin_elementwise_fma((f32x2)(-20.0f), dy, ty);
    f32x2 a0 = x0 + y0, a1 = x0 + ym, a2 = x0 + yp;
    f32x2 a3 = xm + y0, a4 = xm + ym, a5 = xm + yp;
    f32x2 a6 = xp + y0, a7 = xp + ym, a8 = xp + yp;
    f32x2 r0 = {RSQ(a0.x), RSQ(a0.y)};
    f32x2 r1 = {RSQ(a1.x), RSQ(a1.y)};
    f32x2 r2 = {RSQ(a2.x), RSQ(a2.y)};
    f32x2 r3 = {RSQ(a3.x), RSQ(a3.y)};
    f32x2 r4 = {RSQ(a4.x), RSQ(a4.y)};
    f32x2 r5 = {RSQ(a5.x), RSQ(a5.y)};
    f32x2 r6 = {RSQ(a6.x), RSQ(a6.y)};
    f32x2 r7 = {RSQ(a7.x), RSQ(a7.y)};
    f32x2 r8 = {RSQ(a8.x), RSQ(a8.y)};
    return (((r0 + r1) + (r2 + r3)) + ((r4 + r5) + (r6 + r7))) + r8;
}

// Diagonal-safe variant: i==j masked for ALL 9 shifts (reference eye-mask semantics).
__device__ __forceinline__ f32x2 pair9v_masked(f32x2 dx, f32x2 dy, bool dA, bool dB) {
    f32x2 x0 = dx * dx, y0 = dy * dy;
    f32x2 tx = x0 + 100.0f, ty = y0 + 100.0f;
    f32x2 xm = __builtin_elementwise_fma((f32x2)(20.0f), dx, tx);
    f32x2 xp = __builtin_elementwise_fma((f32x2)(-20.0f), dx, tx);
    f32x2 ym = __builtin_elementwise_fma((f32x2)(20.0f), dy, ty);
    f32x2 yp = __builtin_elementwise_fma((f32x2)(-20.0f), dy, ty);
    f32x2 a0 = x0 + y0, a1 = x0 + ym, a2 = x0 + yp;
    f32x2 a3 = xm + y0, a4 = xm + ym, a5 = xm + yp;
    f32x2 a6 = xp + y0, a7 = xp + ym, a8 = xp + yp;
    if (dA) a0.x = 1.0f;
    if (dB) a0.y = 1.0f;
    f32x2 r0 = {RSQ(a0.x), RSQ(a0.y)};
    f32x2 r1 = {RSQ(a1.x), RSQ(a1.y)};
    f32x2 r2 = {RSQ(a2.x), RSQ(a2.y)};
    f32x2 r3 = {RSQ(a3.x), RSQ(a3.y)};
    f32x2 r4 = {RSQ(a4.x), RSQ(a4.y)};
    f32x2 r5 = {RSQ(a5.x), RSQ(a5.y)};
    f32x2 r6 = {RSQ(a6.x), RSQ(a6.y)};
    f32x2 r7 = {RSQ(a7.x), RSQ(a7.y)};
    f32x2 r8 = {RSQ(a8.x), RSQ(a8.y)};
    f32x2 s = (((r0 + r1) + (r2 + r3)) + ((r4 + r5) + (r6 + r7))) + r8;
    if (dA) s.x = 0.0f;
    if (dB) s.y = 0.0f;
    return s;
}

// Triangular 128x128 tiles, j-split by 2, 128-thread blocks (16 blocks/CU residency).
__global__ __launch_bounds__(BLOCK) void pe_kernel(const float* __restrict__ xy,
                                                   float* __restrict__ partial) {
    __shared__ float sx[JSUB];
    __shared__ float sy[JSUB];
    const int t = threadIdx.x;

    // decode triangular index (scalar loop, <=64 SALU iters once per block)
    int rem = blockIdx.x;
    int ib = 0;
    while (rem >= NB - ib) { rem -= NB - ib; ++ib; }
    const int jb = ib + rem;

    const int i = ib * ITILE + t;
    const float2 pi = ((const float2*)xy)[i];
    const f32x2 xiv = {pi.x, pi.x};
    const f32x2 yiv = {pi.y, pi.y};

    const int j0 = jb * ITILE + blockIdx.y * JSUB;
    if (t < JSUB) {
        float2 pj = ((const float2*)xy)[j0 + t];
        sx[t] = pj.x;
        sy[t] = pj.y;
    }
    __syncthreads();

    const f32x2* sxv = (const f32x2*)sx;   // ds_read_b64 broadcast, conflict-free
    const f32x2* syv = (const f32x2*)sy;

    f32x2 accA = {0.0f, 0.0f}, accB = {0.0f, 0.0f};   // two independent chains

    if (ib == jb) {
#pragma unroll 8
        for (int q = 0; q < JSUB / 2; q += 2) {
            f32x2 dxA = xiv - sxv[q],     dyA = yiv - syv[q];
            f32x2 dxB = xiv - sxv[q + 1], dyB = yiv - syv[q + 1];
            int j = j0 + 2 * q;
            accA += pair9v_masked(dxA, dyA, i == j,     i == j + 1);
            accB += pair9v_masked(dxB, dyB, i == j + 2, i == j + 3);
        }
    } else {
#pragma unroll 8
        for (int q = 0; q < JSUB / 2; q += 2) {
            f32x2 dxA = xiv - sxv[q],     dyA = yiv - syv[q];
            f32x2 dxB = xiv - sxv[q + 1], dyB = yiv - syv[q + 1];
            accA += pair9v(dxA, dyA);
            accB += pair9v(dxB, dyB);
        }
        accA += accA;   // weight 2: mirrored (j,i) tile (shift set self-negating)
        accB += accB;
    }

    f32x2 accv = accA + accB;
    float a = accv.x + accv.y;

    // wave-level reduction (deterministic), then combine 2 wave sums via LDS
    for (int off = 32; off > 0; off >>= 1)
        a += __shfl_down(a, off, 64);

    __shared__ float wsum[BLOCK / 64];
    if ((t & 63) == 0) wsum[t >> 6] = a;
    __syncthreads();
    if (t == 0)
        partial[blockIdx.y * NTRI + blockIdx.x] = wsum[0] + wsum[1];
}

// Finisher: reduce NPART block partials + kinetic energy, write scalar.
__global__ __launch_bounds__(1024) void finish_kernel(const float* __restrict__ partial,
                                                      const float* __restrict__ pxy,
                                                      float* __restrict__ out) {
    const int t = threadIdx.x;
    float acc = 0.0f;
    for (int k = t; k < NPART; k += 1024) acc += partial[k];
    for (int k = t; k < 2 * N; k += 1024) {   // KE = sum p^2 / 2
        float p = pxy[k];
        acc += 0.5f * p * p;
    }
    __shared__ float red[1024];
    red[t] = acc;
    __syncthreads();
    for (int s = 512; s > 0; s >>= 1) {
        if (t < s) red[t] += red[t + s];
        __syncthreads();
    }
    if (t == 0) out[0] = red[0];
}

extern "C" void kernel_launch(void* const* d_in, const int* in_sizes, int n_in,
                              void* d_out, int out_size, void* d_ws, size_t ws_size,
                              hipStream_t stream) {
    const float* xy  = (const float*)d_in[0];
    const float* pxy = (const float*)d_in[1];
    float* out       = (float*)d_out;
    float* partial   = (float*)d_ws;   // NPART floats = 16640 B

    dim3 grid(NTRI, JSPLIT);
    pe_kernel<<<grid, BLOCK, 0, stream>>>(xy, partial);
    finish_kernel<<<1, 1024, 0, stream>>>(partial, pxy, out);
}